// Round 10
// baseline (114.174 us; speedup 1.0000x reference)
//
#include <hip/hip_runtime.h>
#include <hip/hip_bf16.h>
#include <cstddef>
#include <cstdint>

#define BATCH 4
#define CDIM 256
#define HW 4096
#define MCTX 1024
#define CTX 256
#define HEADS 8
#define DHEAD 64
#define INNER 512

typedef __attribute__((ext_vector_type(8))) short bf16x8;
typedef __attribute__((ext_vector_type(4))) float f32x4;
typedef __attribute__((ext_vector_type(16))) float f32x16;

static __device__ __forceinline__ ushort f2bf(float f) {
  __hip_bfloat16 h = __float2bfloat16(f);
  return *reinterpret_cast<ushort*>(&h);
}

// async global->LDS, 16B per lane. LDS dest is wave-uniform base + lane*16.
static __device__ __forceinline__ void gload16(const void* g, void* l) {
  __builtin_amdgcn_global_load_lds(
      (const __attribute__((address_space(1))) void*)(uintptr_t)g,
      (__attribute__((address_space(3))) void*)(uint32_t)(uintptr_t)l,
      16, 0, 0);
}

// ---------------------------------------------------------------------------
// LN over channels of x with layout transpose. x:[b,256,4096] -> xn:[b,4096,256]
// Load phase vectorized: float4 per lane along n (G13).
// ---------------------------------------------------------------------------
__global__ __launch_bounds__(256) void ln_x_kernel(
    const float* __restrict__ x, const float* __restrict__ g,
    const float* __restrict__ bta, float* __restrict__ xn,
    ushort* __restrict__ xnbf) {
  const int blk = blockIdx.x;
  const int bi = blk / (HW / 32);
  const int n0 = (blk % (HW / 32)) * 32;
  __shared__ float xt[32][257];
  __shared__ float smu[32], srs[32];
  const int t = threadIdx.x;
  const float* xb = x + (size_t)bi * CDIM * HW;
  {
    const int cr = t >> 3;            // c within pass (32 per pass)
    const int n4 = (t & 7) * 4;       // 8 lanes x float4 cover 32 n
    #pragma unroll
    for (int pass = 0; pass < 8; ++pass) {
      const int c = pass * 32 + cr;
      float4 v = *(const float4*)(xb + (size_t)c * HW + n0 + n4);
      xt[n4 + 0][c] = v.x; xt[n4 + 1][c] = v.y;
      xt[n4 + 2][c] = v.z; xt[n4 + 3][c] = v.w;
    }
  }
  __syncthreads();
  const int col = t >> 3, j = t & 7;
  float s = 0.f, ss = 0.f;
  #pragma unroll
  for (int c = j; c < CDIM; c += 8) {
    float v = xt[col][c];
    s += v; ss += v * v;
  }
  #pragma unroll
  for (int off = 1; off < 8; off <<= 1) {
    s += __shfl_xor(s, off);
    ss += __shfl_xor(ss, off);
  }
  if (j == 0) {
    float mu = s * (1.f / CDIM);
    smu[col] = mu;
    srs[col] = rsqrtf(ss * (1.f / CDIM) - mu * mu + 1e-5f);
  }
  __syncthreads();
  const float gv = g[t], bvv = bta[t];
  float* xnb = xn + ((size_t)bi * HW + n0) * CDIM;
  ushort* xbb = xnbf + ((size_t)bi * HW + n0) * CDIM;
  #pragma unroll 4
  for (int n = 0; n < 32; ++n) {
    float val = (xt[n][t] - smu[n]) * srs[n] * gv + bvv;
    xnb[(size_t)n * CDIM + t] = val;
    xbb[(size_t)n * CDIM + t] = f2bf(val);
  }
}

// ---------------------------------------------------------------------------
// LN y rows -> bf16. 4 waves per block, one row each.
// ---------------------------------------------------------------------------
__global__ __launch_bounds__(256) void ln_y_kernel(
    const float* __restrict__ y, const float* __restrict__ g,
    const float* __restrict__ bta, ushort* __restrict__ ynbf) {
  const int row = blockIdx.x * 4 + (threadIdx.x >> 6);
  const int t = threadIdx.x & 63;
  float4 v = ((const float4*)(y + (size_t)row * CTX))[t];
  float s = v.x + v.y + v.z + v.w;
  float ss = v.x * v.x + v.y * v.y + v.z * v.z + v.w * v.w;
  #pragma unroll
  for (int off = 1; off < 64; off <<= 1) {
    s += __shfl_xor(s, off);
    ss += __shfl_xor(ss, off);
  }
  float mu = s * (1.f / CTX);
  float rs = rsqrtf(ss * (1.f / CTX) - mu * mu + 1e-5f);
  float4 gv = ((const float4*)g)[t];
  float4 b4 = ((const float4*)bta)[t];
  ushort4 ob;
  ob.x = f2bf((v.x - mu) * rs * gv.x + b4.x);
  ob.y = f2bf((v.y - mu) * rs * gv.y + b4.y);
  ob.z = f2bf((v.z - mu) * rs * gv.z + b4.z);
  ob.w = f2bf((v.w - mu) * rs * gv.w + b4.w);
  *(ushort4*)(ynbf + (size_t)row * CTX + t * 4) = ob;
}

// ---------------------------------------------------------------------------
// Weight prep: W [K][N] fp32 -> Wt [N][K] bf16 (64x64 LDS transpose tiles).
// wprep4: ALL FOUR weights in ONE launch. z<3: Wq/Wk/Wv (256x512, grid 8x4).
// z==3: Wo (512x256) — bijective remap (x,y)->(x&3, y*2+(x>>2)) gives 4x8.
// ---------------------------------------------------------------------------
static __device__ __forceinline__ void wprep_body(
    const float* __restrict__ W, ushort* __restrict__ Wt, int K, int N,
    int bx, int by) {
  __shared__ ushort T[64][65];
  const int k0 = by * 64, n0 = bx * 64;
  const int t = threadIdx.x;
  #pragma unroll
  for (int rr = 0; rr < 4; ++rr) {
    int row = rr * 16 + (t >> 4);          // k
    int c = (t & 15) * 4;                  // n
    float4 wv = *(const float4*)(W + (size_t)(k0 + row) * N + n0 + c);
    T[row][c + 0] = f2bf(wv.x); T[row][c + 1] = f2bf(wv.y);
    T[row][c + 2] = f2bf(wv.z); T[row][c + 3] = f2bf(wv.w);
  }
  __syncthreads();
  #pragma unroll
  for (int rr = 0; rr < 4; ++rr) {
    int nrow = rr * 16 + (t >> 4);
    int kc = (t & 15) * 4;
    ushort4 o;
    o.x = T[kc + 0][nrow]; o.y = T[kc + 1][nrow];
    o.z = T[kc + 2][nrow]; o.w = T[kc + 3][nrow];
    *(ushort4*)(Wt + (size_t)(n0 + nrow) * K + k0 + kc) = o;
  }
}

__global__ __launch_bounds__(256) void wprep4_kernel(
    const float* __restrict__ W0, const float* __restrict__ W1,
    const float* __restrict__ W2, const float* __restrict__ W3,
    ushort* __restrict__ T0, ushort* __restrict__ T1,
    ushort* __restrict__ T2, ushort* __restrict__ T3) {
  const int z = blockIdx.z;
  if (z < 3) {
    const float* W = (z == 0) ? W0 : (z == 1) ? W1 : W2;
    ushort* Wt = (z == 0) ? T0 : (z == 1) ? T1 : T2;
    wprep_body(W, Wt, 256, 512, blockIdx.x, blockIdx.y);
  } else {
    wprep_body(W3, T3, 512, 256, blockIdx.x & 3,
               blockIdx.y * 2 + (blockIdx.x >> 2));
  }
}

// ---------------------------------------------------------------------------
// bf16 MFMA GEMM body: C[M][N] = A[M][K] @ Bt[N][K]^T, 128x128 tile, BK=64,
// 4 waves (2x2), each wave 64x64 = 4x4 tiles of 16x16x32 mfma.
// Staging via global_load_lds; swizzle per rule #21 (linear LDS dest,
// pre-swizzled global source col, matching read-side XOR).
// Optional vt_out: write C transposed per-head ([b*h][d][m]) instead of
// row-major — fuses the old vtr kernel into the V-projection epilogue.
// ---------------------------------------------------------------------------
template <bool F32_RES_OUT>
static __device__ __forceinline__ void gemm_body(
    const ushort* __restrict__ A, const ushort* __restrict__ Bt,
    const float* __restrict__ bias, const float* __restrict__ res,
    void* __restrict__ Cout, ushort* __restrict__ vt_out,
    int M, int N, int K, float scale, int m0, int n0) {
  __shared__ ushort As[128 * 64];   // linear, 16 KiB
  __shared__ ushort Bs[128 * 64];
  const int t = threadIdx.x;
  const int l = t & 63, w = t >> 6;
  const int lq = l & 15, lg = l >> 4;
  const int wr = w >> 1, wc = w & 1;
  f32x4 acc[4][4];
  #pragma unroll
  for (int mt = 0; mt < 4; ++mt)
    #pragma unroll
    for (int nt = 0; nt < 4; ++nt)
      #pragma unroll
      for (int e = 0; e < 4; ++e) acc[mt][nt][e] = 0.f;
  // staging geometry: chunk C = i*256 + w*64 + l covers row C>>3 (= i*32 +
  // w*8 + (l>>3)), source col pre-swizzled ((l&7)^(row&7))*8; row&7 == l>>3.
  const int srow = w * 8 + (l >> 3);
  const int scol = ((l & 7) ^ (l >> 3)) * 8;
  const ushort* pA = A + (size_t)(m0 + srow) * K + scol;
  const ushort* pB = Bt + (size_t)(n0 + srow) * K + scol;
  const int dbase = w * 512;               // shorts (wave chunk base)
  for (int k0 = 0; k0 < K; k0 += 64) {
    if (k0) __syncthreads();               // prior reads done before overwrite
    #pragma unroll
    for (int i = 0; i < 4; ++i) {
      gload16(pA + (size_t)(i * 32) * K + k0, &As[i * 2048 + dbase]);
      gload16(pB + (size_t)(i * 32) * K + k0, &Bs[i * 2048 + dbase]);
    }
    __syncthreads();                       // drains vmcnt -> tile visible
    #pragma unroll
    for (int ks = 0; ks < 2; ++ks) {
      bf16x8 af[4], bfr[4];
      #pragma unroll
      for (int mt = 0; mt < 4; ++mt) {
        const int R = wr * 64 + mt * 16 + lq;
        af[mt] = *(const bf16x8*)(
            &As[R * 64 + ((ks * 32 + lg * 8) ^ ((R & 7) * 8))]);
      }
      #pragma unroll
      for (int nt = 0; nt < 4; ++nt) {
        const int R = wc * 64 + nt * 16 + lq;
        bfr[nt] = *(const bf16x8*)(
            &Bs[R * 64 + ((ks * 32 + lg * 8) ^ ((R & 7) * 8))]);
      }
      #pragma unroll
      for (int mt = 0; mt < 4; ++mt)
        #pragma unroll
        for (int nt = 0; nt < 4; ++nt)
          acc[mt][nt] = __builtin_amdgcn_mfma_f32_16x16x32_bf16(
              af[mt], bfr[nt], acc[mt][nt], 0, 0, 0);
    }
  }
  #pragma unroll
  for (int nt = 0; nt < 4; ++nt) {
    const int colc = n0 + wc * 64 + nt * 16 + lq;
    const float bcol = bias ? bias[colc] : 0.f;
    #pragma unroll
    for (int mt = 0; mt < 4; ++mt) {
      #pragma unroll
      for (int i = 0; i < 4; ++i) {
        const size_t row = (size_t)(m0 + wr * 64 + mt * 16 + lg * 4 + i);
        float v = acc[mt][nt][i] * scale + bcol;
        if (vt_out) {
          // transposed per-head: vt[(bi*8+h)*64 + d][m], h=colc>>6, d=colc&63
          vt_out[(size_t)((((row >> 10) * 8 + (colc >> 6)) << 6) + (colc & 63)) * MCTX
                 + (row & (MCTX - 1))] = f2bf(v);
        } else if (F32_RES_OUT) {
          ((float*)Cout)[row * N + colc] = v + res[row * N + colc];
        } else {
          ((ushort*)Cout)[row * N + colc] = f2bf(v);
        }
      }
    }
  }
}

template <bool F32_RES_OUT>
__global__ __launch_bounds__(256) void mfma_gemm(
    const ushort* __restrict__ A, const ushort* __restrict__ Bt,
    const float* __restrict__ bias, const float* __restrict__ res,
    void* __restrict__ Cout, int M, int N, int K, float scale) {
  gemm_body<F32_RES_OUT>(A, Bt, bias, res, Cout, nullptr, M, N, K, scale,
                         blockIdx.y * 128, blockIdx.x * 128);
}

// K and V projection GEMMs in one launch (shared A = ynbf). V half writes
// the transposed per-head layout directly (old vtr kernel fused away).
__global__ __launch_bounds__(256) void mfma_gemm_kv(
    const ushort* __restrict__ A, const ushort* __restrict__ BtK,
    const ushort* __restrict__ BtV, const float* __restrict__ bv,
    ushort* __restrict__ Ck, ushort* __restrict__ vt_out) {
  const bool isV = blockIdx.x >= 4;
  gemm_body<false>(A, isV ? BtV : BtK, isV ? bv : nullptr, nullptr,
                   (void*)Ck, isV ? vt_out : nullptr, 4096, 512, 256, 1.f,
                   blockIdx.y * 128, (blockIdx.x & 3) * 128);
}

// ---------------------------------------------------------------------------
// Flash attention, bf16 MFMA, 32x32 tiles + in-register P via permlane swap.
// q:[b*n][512] pre-scaled 0.125*log2e; k:[b*m][512]; vt:[b*h][64 d][1024 m].
// Block: (b,h) x 256 q-rows; 8 waves x 32 q-rows (one 32x32 group per wave).
// QK^T: St[2] = mfma_32x32x16(K-frag, Q-frag) over d=64 (8 mfma/tile).
// C-layout (m74/m101): col=q=lane&31, row=key=(reg&3)+8*(reg>>2)+4*(lane>>5).
// Softmax fully in-lane (32 vals) + one shfl_xor(32); exp2 domain; defer-max.
// P -> PV A-frags IN REGISTERS: pack pairs to bf16 words, then
// v_permlane32_swap_b32 exchanges lo-half<->hi-half words so each lane holds
// A[q=lane&31][k=(lane>>5)*8+e] — frag=[Sa,Sb,Da,Db] valid for BOTH halves.
// PV: 8 mfma_32x32x16 (A=P regs, B=V from Vs[d][key], b128 reads).
// vs r7/r9 structure: MFMA issue 160->128 cy/tile/wave (32x32 = 25% cheaper
// per FLOP, m119), Ps LDS buffer + 12 LDS ops + serial P round-trip deleted,
// LDS 64->32 KiB. Staging/double-buffer/XCD-swizzle/stagger unchanged.
// LEDGER (do not revisit): 4-wave blocks -13% (r5); gload_lds K/V staging in
// attn -13% (r5); min-waves>4 spills catastrophically (r3); K=16 16x16 PV -7%
// (r8: doubles MFMA issue); intra-tile reorder flat (r4).
// ---------------------------------------------------------------------------
__global__ __launch_bounds__(512, 4) void attn_mfma(
    const ushort* __restrict__ q, const ushort* __restrict__ k,
    const ushort* __restrict__ vt, ushort* __restrict__ ao) {
  // XCD-aware swizzle (bijective: 512 = 8 * 64)
  const int bid = blockIdx.x + 16 * (blockIdx.y + 8 * blockIdx.z);
  const int swz = (bid & 7) * 64 + (bid >> 3);
  const int bi = swz >> 7;
  const int h = (swz >> 4) & 7;
  const int n0 = (swz & 15) * 256;
  const int tile0 = (bid & 3) << 2;        // phase stagger: 0,4,8,12
  __shared__ ushort Ks[2][64 * 64];
  __shared__ ushort Vs[2][64 * 64];
  const int t = threadIdx.x;
  const int l = t & 63, w = t >> 6;
  const int lq32 = l & 31, hi = l >> 5;

  // Q fragments (B operand of QK: B[k=d][col=q], k=(lane>>5)*8+e per d-step)
  bf16x8 bq[4];
  {
    const size_t qrow = (size_t)(bi * HW + n0 + w * 32 + lq32);
    #pragma unroll
    for (int ds = 0; ds < 4; ++ds)
      bq[ds] = *(const bf16x8*)(q + qrow * INNER + h * DHEAD + ds * 16 + hi * 8);
  }

  float m_run = -1e30f, l_run = 0.f;
  f32x16 oacc[2];                           // O[q][d], d-tiles of 32
  #pragma unroll
  for (int dt = 0; dt < 2; ++dt)
    #pragma unroll
    for (int e = 0; e < 16; ++e) oacc[dt][e] = 0.f;

  // staging: 64x64 bf16 tile = 512 uint4; 512 threads -> 1 uint4 each per tile
  const int rr = t >> 3, cc = (t & 7) * 8;
  const ushort* kptr = k + (size_t)(bi * MCTX + rr) * INNER + h * DHEAD + cc;
  const ushort* vptr = vt + (size_t)((bi * HEADS + h) * 64 + rr) * MCTX + cc;
  const int sidx = (rr * 64 + cc) ^ ((rr & 7) << 3);

  {  // stage first tile (tile0) into buffer 0
    const int ms = tile0 << 6;
    uint4 k0v = *(const uint4*)(kptr + (size_t)ms * INNER);
    uint4 v0v = *(const uint4*)(vptr + ms);
    *(uint4*)(&Ks[0][sidx]) = k0v;
    *(uint4*)(&Vs[0][sidx]) = v0v;
  }
  __syncthreads();

  for (int it = 0; it < 16; ++it) {
    const int buf = it & 1;
    const bool more = (it + 1) < 16;
    const int mnext = ((tile0 + it + 1) & 15) << 6;
    uint4 kpre{}, vpre{};
    if (more) {  // prefetch next tile; staged to LDS after softmax
      kpre = *(const uint4*)(kptr + (size_t)mnext * INNER);
      vpre = *(const uint4*)(vptr + mnext);
    }
    // QK^T: St[kt][key=32kt+row][q=lane&31] over d=64, A=K-frag from Ks
    f32x16 sc[2];
    #pragma unroll
    for (int kt = 0; kt < 2; ++kt)
      #pragma unroll
      for (int e = 0; e < 16; ++e) sc[kt][e] = 0.f;
    __builtin_amdgcn_s_setprio(1);
    #pragma unroll
    for (int kt = 0; kt < 2; ++kt) {
      #pragma unroll
      for (int ds = 0; ds < 4; ++ds) {
        const int krow = kt * 32 + lq32;
        bf16x8 ak = *(const bf16x8*)(
            &Ks[buf][(krow * 64 + ds * 16 + hi * 8) ^ ((krow & 7) << 3)]);
        sc[kt] = __builtin_amdgcn_mfma_f32_32x32x16_bf16(ak, bq[ds], sc[kt], 0, 0, 0);
      }
    }
    __builtin_amdgcn_s_setprio(0);
    // ---- softmax (q = lane&31; lanes l, l+32 hold complementary keys) ----
    f32x16 mx;
    #pragma unroll
    for (int e = 0; e < 16; ++e) mx[e] = fmaxf(sc[0][e], sc[1][e]);
    #pragma unroll
    for (int e = 0; e < 8; ++e) mx[e] = fmaxf(mx[e], mx[e + 8]);
    #pragma unroll
    for (int e = 0; e < 4; ++e) mx[e] = fmaxf(mx[e], mx[e + 4]);
    float mloc = fmaxf(fmaxf(mx[0], mx[1]), fmaxf(mx[2], mx[3]));
    mloc = fmaxf(mloc, __shfl_xor(mloc, 32));
    // defer-max: only rescale when some q-row's max grew by > 8 (log2 units)
    if (!__all((int)(mloc - m_run <= 8.f))) {
      const float mnew = fmaxf(m_run, mloc);
      const float corr = __builtin_amdgcn_exp2f(m_run - mnew);
      l_run *= corr;
      m_run = mnew;
      #pragma unroll
      for (int r = 0; r < 16; ++r) {
        const int qrow = (r & 3) + 8 * (r >> 2) + 4 * hi;
        float ci = __shfl(corr, qrow);
        oacc[0][r] *= ci; oacc[1][r] *= ci;
      }
    }
    #pragma unroll
    for (int kt = 0; kt < 2; ++kt)
      #pragma unroll
      for (int e = 0; e < 16; ++e)
        sc[kt][e] = __builtin_amdgcn_exp2f(sc[kt][e] - m_run);
    f32x16 s16;
    #pragma unroll
    for (int e = 0; e < 16; ++e) s16[e] = sc[0][e] + sc[1][e];
    #pragma unroll
    for (int e = 0; e < 8; ++e) s16[e] += s16[e + 8];
    #pragma unroll
    for (int e = 0; e < 4; ++e) s16[e] += s16[e + 4];
    float psum = (s16[0] + s16[1]) + (s16[2] + s16[3]);
    psum += __shfl_xor(psum, 32);
    l_run += psum;
    // ---- P -> PV A-frags in registers (pack + permlane32_swap) ----
    // words: wa(rr)=keys 8rr+4hi+{0,1}, wb(rr)=+{2,3} (rr=0..3 per 32-tile).
    // swap(D=wa(2p+1), S=wa(2p)) -> frag(keys 16p..16p+15) = [Sa,Sb,Da,Db]
    // for BOTH lane halves (lo: own rr'=2p + partner rr'; hi: partner rr''
    // =2p+1 + own rr'').
    bf16x8 pafr[4];
    #pragma unroll
    for (int kt = 0; kt < 2; ++kt) {
      uint wa[4], wb[4];
      #pragma unroll
      for (int r4 = 0; r4 < 4; ++r4) {
        wa[r4] = (uint)f2bf(sc[kt][4 * r4]) | ((uint)f2bf(sc[kt][4 * r4 + 1]) << 16);
        wb[r4] = (uint)f2bf(sc[kt][4 * r4 + 2]) | ((uint)f2bf(sc[kt][4 * r4 + 3]) << 16);
      }
      #pragma unroll
      for (int p2 = 0; p2 < 2; ++p2) {
        uint Sa = wa[2 * p2], Da = wa[2 * p2 + 1];
        uint Sb = wb[2 * p2], Db = wb[2 * p2 + 1];
        asm volatile("v_permlane32_swap_b32 %0, %1" : "+v"(Da), "+v"(Sa));
        asm volatile("v_permlane32_swap_b32 %0, %1" : "+v"(Db), "+v"(Sb));
        uint4 fr;
        fr.x = Sa; fr.y = Sb; fr.z = Da; fr.w = Db;
        pafr[kt * 2 + p2] = *reinterpret_cast<bf16x8*>(&fr);
      }
    }
    // stage next tile into the other buffer (safe: buf^1 last read before
    // the previous barrier); drains during PV
    if (more) {
      *(uint4*)(&Ks[buf ^ 1][sidx]) = kpre;
      *(uint4*)(&Vs[buf ^ 1][sidx]) = vpre;
    }
    // ---- PV: O[q][d] += P @ V, B-frag = V[key][d] from Vs[d][key] ----
    __builtin_amdgcn_s_setprio(1);
    #pragma unroll
    for (int dt = 0; dt < 2; ++dt) {
      const int vrow = dt * 32 + lq32;
      #pragma unroll
      for (int kt16 = 0; kt16 < 4; ++kt16) {
        bf16x8 vb = *(const bf16x8*)(
            &Vs[buf][(vrow * 64 + kt16 * 16 + hi * 8) ^ ((vrow & 7) << 3)]);
        oacc[dt] = __builtin_amdgcn_mfma_f32_32x32x16_bf16(pafr[kt16], vb, oacc[dt], 0, 0, 0);
      }
    }
    __builtin_amdgcn_s_setprio(0);
    __syncthreads();
  }
  const float rl = 1.f / l_run;
  #pragma unroll
  for (int r = 0; r < 16; ++r) {
    const int qrow = (r & 3) + 8 * (r >> 2) + 4 * hi;
    float li = __shfl(rl, qrow);
    const size_t row = (size_t)(bi * HW + n0 + w * 32 + qrow);
    ao[row * INNER + h * DHEAD + lq32] = f2bf(oacc[0][r] * li);
    ao[row * INNER + h * DHEAD + 32 + lq32] = f2bf(oacc[1][r] * li);
  }
}

// ---------------------------------------------------------------------------
extern "C" void kernel_launch(void* const* d_in, const int* in_sizes, int n_in,
                              void* d_out, int out_size, void* d_ws, size_t ws_size,
                              hipStream_t stream) {
  const float* x     = (const float*)d_in[0];
  const float* y     = (const float*)d_in[1];
  const float* ln_xg = (const float*)d_in[2];
  const float* ln_xb = (const float*)d_in[3];
  const float* ln_yg = (const float*)d_in[4];
  const float* ln_yb = (const float*)d_in[5];
  const float* Wq    = (const float*)d_in[6];
  const float* Wk    = (const float*)d_in[7];
  const float* Wv    = (const float*)d_in[8];
  const float* bv    = (const float*)d_in[9];
  const float* Wo    = (const float*)d_in[10];
  const float* bo    = (const float*)d_in[11];
  float* out = (float*)d_out;

  char* p = (char*)d_ws;
  float*  xn   = (float*)p;  p += (size_t)16384 * 256 * 4;
  ushort* xnbf = (ushort*)p; p += (size_t)16384 * 256 * 2;
  ushort* ynbf = (ushort*)p; p += (size_t)4096 * 256 * 2;
  ushort* wtq  = (ushort*)p; p += (size_t)512 * 256 * 2;
  ushort* wtk  = (ushort*)p; p += (size_t)512 * 256 * 2;
  ushort* wtv  = (ushort*)p; p += (size_t)512 * 256 * 2;
  ushort* wto  = (ushort*)p; p += (size_t)256 * 512 * 2;
  ushort* qbf  = (ushort*)p; p += (size_t)16384 * 512 * 2;
  ushort* kbf  = (ushort*)p; p += (size_t)4096 * 512 * 2;
  ushort* vtb  = (ushort*)p; p += (size_t)4096 * 512 * 2;
  ushort* aobf = (ushort*)p; p += (size_t)16384 * 512 * 2;

  wprep4_kernel<<<dim3(8, 4, 4), 256, 0, stream>>>(
      Wq, Wk, Wv, Wo, wtq, wtk, wtv, wto);
  ln_x_kernel<<<dim3(BATCH * (HW / 32)), 256, 0, stream>>>(x, ln_xg, ln_xb, xn, xnbf);
  ln_y_kernel<<<dim3(BATCH * MCTX / 4), 256, 0, stream>>>(y, ln_yg, ln_yb, ynbf);
  // q = (xn @ Wq) * 0.125 * log2(e)  (scale folded; softmax runs in exp2 domain)
  mfma_gemm<false><<<dim3(4, 128), 256, 0, stream>>>(
      xnbf, wtq, nullptr, nullptr, qbf, 16384, 512, 256, 0.1803368801111204f);
  // K + V projections; V written directly in transposed per-head layout
  mfma_gemm_kv<<<dim3(8, 32), 256, 0, stream>>>(ynbf, wtk, wtv, bv, kbf, vtb);
  attn_mfma<<<dim3(HW / 256, HEADS, BATCH), 512, 0, stream>>>(qbf, kbf, vtb, aobf);
  // out = ao @ Wo + bo + xn
  mfma_gemm<true><<<dim3(2, 128), 256, 0, stream>>>(
      aobf, wto, bo, xn, out, 16384, 256, 512, 1.f);
}

// Round 11
// 104.349 us; speedup vs baseline: 1.0942x; 1.0942x over previous
//
#include <hip/hip_runtime.h>
#include <hip/hip_bf16.h>
#include <cstddef>
#include <cstdint>

#define BATCH 4
#define CDIM 256
#define HW 4096
#define MCTX 1024
#define CTX 256
#define HEADS 8
#define DHEAD 64
#define INNER 512

typedef __attribute__((ext_vector_type(8))) short bf16x8;
typedef __attribute__((ext_vector_type(4))) float f32x4;
typedef __attribute__((ext_vector_type(16))) float f32x16;

static __device__ __forceinline__ ushort f2bf(float f) {
  __hip_bfloat16 h = __float2bfloat16(f);
  return *reinterpret_cast<ushort*>(&h);
}

// async global->LDS, 16B per lane. LDS dest is wave-uniform base + lane*16.
static __device__ __forceinline__ void gload16(const void* g, void* l) {
  __builtin_amdgcn_global_load_lds(
      (const __attribute__((address_space(1))) void*)(uintptr_t)g,
      (__attribute__((address_space(3))) void*)(uint32_t)(uintptr_t)l,
      16, 0, 0);
}

// ---------------------------------------------------------------------------
// LN over channels of x with layout transpose. x:[b,256,4096] -> xn:[b,4096,256]
// Load phase vectorized: float4 per lane along n (G13).
// ---------------------------------------------------------------------------
static __device__ __forceinline__ void ln_x_body(
    const float* __restrict__ x, const float* __restrict__ g,
    const float* __restrict__ bta, float* __restrict__ xn,
    ushort* __restrict__ xnbf, int blk) {
  const int bi = blk / (HW / 32);
  const int n0 = (blk % (HW / 32)) * 32;
  __shared__ float xt[32][257];
  __shared__ float smu[32], srs[32];
  const int t = threadIdx.x;
  const float* xb = x + (size_t)bi * CDIM * HW;
  {
    const int cr = t >> 3;            // c within pass (32 per pass)
    const int n4 = (t & 7) * 4;       // 8 lanes x float4 cover 32 n
    #pragma unroll
    for (int pass = 0; pass < 8; ++pass) {
      const int c = pass * 32 + cr;
      float4 v = *(const float4*)(xb + (size_t)c * HW + n0 + n4);
      xt[n4 + 0][c] = v.x; xt[n4 + 1][c] = v.y;
      xt[n4 + 2][c] = v.z; xt[n4 + 3][c] = v.w;
    }
  }
  __syncthreads();
  const int col = t >> 3, j = t & 7;
  float s = 0.f, ss = 0.f;
  #pragma unroll
  for (int c = j; c < CDIM; c += 8) {
    float v = xt[col][c];
    s += v; ss += v * v;
  }
  #pragma unroll
  for (int off = 1; off < 8; off <<= 1) {
    s += __shfl_xor(s, off);
    ss += __shfl_xor(ss, off);
  }
  if (j == 0) {
    float mu = s * (1.f / CDIM);
    smu[col] = mu;
    srs[col] = rsqrtf(ss * (1.f / CDIM) - mu * mu + 1e-5f);
  }
  __syncthreads();
  const float gv = g[t], bvv = bta[t];
  float* xnb = xn + ((size_t)bi * HW + n0) * CDIM;
  ushort* xbb = xnbf + ((size_t)bi * HW + n0) * CDIM;
  #pragma unroll 4
  for (int n = 0; n < 32; ++n) {
    float val = (xt[n][t] - smu[n]) * srs[n] * gv + bvv;
    xnb[(size_t)n * CDIM + t] = val;
    xbb[(size_t)n * CDIM + t] = f2bf(val);
  }
}

// ---------------------------------------------------------------------------
// LN y rows -> bf16. 4 waves per block, one row each.
// ---------------------------------------------------------------------------
static __device__ __forceinline__ void ln_y_body(
    const float* __restrict__ y, const float* __restrict__ g,
    const float* __restrict__ bta, ushort* __restrict__ ynbf, int blk) {
  const int row = blk * 4 + (threadIdx.x >> 6);
  const int t = threadIdx.x & 63;
  float4 v = ((const float4*)(y + (size_t)row * CTX))[t];
  float s = v.x + v.y + v.z + v.w;
  float ss = v.x * v.x + v.y * v.y + v.z * v.z + v.w * v.w;
  #pragma unroll
  for (int off = 1; off < 64; off <<= 1) {
    s += __shfl_xor(s, off);
    ss += __shfl_xor(ss, off);
  }
  float mu = s * (1.f / CTX);
  float rs = rsqrtf(ss * (1.f / CTX) - mu * mu + 1e-5f);
  float4 gv = ((const float4*)g)[t];
  float4 b4 = ((const float4*)bta)[t];
  ushort4 ob;
  ob.x = f2bf((v.x - mu) * rs * gv.x + b4.x);
  ob.y = f2bf((v.y - mu) * rs * gv.y + b4.y);
  ob.z = f2bf((v.z - mu) * rs * gv.z + b4.z);
  ob.w = f2bf((v.w - mu) * rs * gv.w + b4.w);
  *(ushort4*)(ynbf + (size_t)row * CTX + t * 4) = ob;
}

// ---------------------------------------------------------------------------
// Weight prep: W [K][N] fp32 -> Wt [N][K] bf16 (64x64 LDS transpose tiles).
// ---------------------------------------------------------------------------
static __device__ __forceinline__ void wprep_body(
    const float* __restrict__ W, ushort* __restrict__ Wt, int K, int N,
    int bx, int by) {
  __shared__ ushort T[64][65];
  const int k0 = by * 64, n0 = bx * 64;
  const int t = threadIdx.x;
  #pragma unroll
  for (int rr = 0; rr < 4; ++rr) {
    int row = rr * 16 + (t >> 4);          // k
    int c = (t & 15) * 4;                  // n
    float4 wv = *(const float4*)(W + (size_t)(k0 + row) * N + n0 + c);
    T[row][c + 0] = f2bf(wv.x); T[row][c + 1] = f2bf(wv.y);
    T[row][c + 2] = f2bf(wv.z); T[row][c + 3] = f2bf(wv.w);
  }
  __syncthreads();
  #pragma unroll
  for (int rr = 0; rr < 4; ++rr) {
    int nrow = rr * 16 + (t >> 4);
    int kc = (t & 15) * 4;
    ushort4 o;
    o.x = T[kc + 0][nrow]; o.y = T[kc + 1][nrow];
    o.z = T[kc + 2][nrow]; o.w = T[kc + 3][nrow];
    *(ushort4*)(Wt + (size_t)(n0 + nrow) * K + k0 + kc) = o;
  }
}

// ---------------------------------------------------------------------------
// MERGED PREP: ln_x (512 blocks, the long pole, scheduled first) + ln_y
// (1024) + all four weight transposes (128). One dispatch replaces three —
// removes two full-device drain/launch boundaries; small kernels fill the
// CUs alongside ln_x's memory-bound blocks.
// ---------------------------------------------------------------------------
__global__ __launch_bounds__(256) void prep_kernel(
    const float* __restrict__ x, const float* __restrict__ ln_xg,
    const float* __restrict__ ln_xb, float* __restrict__ xn,
    ushort* __restrict__ xnbf,
    const float* __restrict__ y, const float* __restrict__ ln_yg,
    const float* __restrict__ ln_yb, ushort* __restrict__ ynbf,
    const float* __restrict__ Wq, const float* __restrict__ Wk,
    const float* __restrict__ Wv, const float* __restrict__ Wo,
    ushort* __restrict__ wtq, ushort* __restrict__ wtk,
    ushort* __restrict__ wtv, ushort* __restrict__ wto) {
  const int id = blockIdx.x;
  if (id < 512) {
    ln_x_body(x, ln_xg, ln_xb, xn, xnbf, id);
  } else if (id < 1536) {
    ln_y_body(y, ln_yg, ln_yb, ynbf, id - 512);
  } else {
    const int r = id - 1536;                 // 0..127
    const int z = r >> 5, rem = r & 31;
    const int bx = rem & 7, by = rem >> 3;
    if (z < 3) {
      const float* W = (z == 0) ? Wq : (z == 1) ? Wk : Wv;
      ushort* Wt = (z == 0) ? wtq : (z == 1) ? wtk : wtv;
      wprep_body(W, Wt, 256, 512, bx, by);
    } else {
      wprep_body(Wo, wto, 512, 256, bx & 3, by * 2 + (bx >> 2));
    }
  }
}

// ---------------------------------------------------------------------------
// bf16 MFMA GEMM body: C[M][N] = A[M][K] @ Bt[N][K]^T, 128x128 tile, BK=64,
// 4 waves (2x2), each wave 64x64 = 4x4 tiles of 16x16x32 mfma.
// Staging via global_load_lds; swizzle per rule #21 (linear LDS dest,
// pre-swizzled global source col, matching read-side XOR).
// Optional vt_out: write C transposed per-head ([b*h][d][m]) instead of
// row-major — fuses the old vtr kernel into the V-projection epilogue.
// ---------------------------------------------------------------------------
template <bool F32_RES_OUT>
static __device__ __forceinline__ void gemm_body(
    const ushort* __restrict__ A, const ushort* __restrict__ Bt,
    const float* __restrict__ bias, const float* __restrict__ res,
    void* __restrict__ Cout, ushort* __restrict__ vt_out,
    int M, int N, int K, float scale, int m0, int n0) {
  __shared__ ushort As[128 * 64];   // linear, 16 KiB
  __shared__ ushort Bs[128 * 64];
  const int t = threadIdx.x;
  const int l = t & 63, w = t >> 6;
  const int lq = l & 15, lg = l >> 4;
  const int wr = w >> 1, wc = w & 1;
  f32x4 acc[4][4];
  #pragma unroll
  for (int mt = 0; mt < 4; ++mt)
    #pragma unroll
    for (int nt = 0; nt < 4; ++nt)
      #pragma unroll
      for (int e = 0; e < 4; ++e) acc[mt][nt][e] = 0.f;
  // staging geometry: chunk C = i*256 + w*64 + l covers row C>>3 (= i*32 +
  // w*8 + (l>>3)), source col pre-swizzled ((l&7)^(row&7))*8; row&7 == l>>3.
  const int srow = w * 8 + (l >> 3);
  const int scol = ((l & 7) ^ (l >> 3)) * 8;
  const ushort* pA = A + (size_t)(m0 + srow) * K + scol;
  const ushort* pB = Bt + (size_t)(n0 + srow) * K + scol;
  const int dbase = w * 512;               // shorts (wave chunk base)
  for (int k0 = 0; k0 < K; k0 += 64) {
    if (k0) __syncthreads();               // prior reads done before overwrite
    #pragma unroll
    for (int i = 0; i < 4; ++i) {
      gload16(pA + (size_t)(i * 32) * K + k0, &As[i * 2048 + dbase]);
      gload16(pB + (size_t)(i * 32) * K + k0, &Bs[i * 2048 + dbase]);
    }
    __syncthreads();                       // drains vmcnt -> tile visible
    #pragma unroll
    for (int ks = 0; ks < 2; ++ks) {
      bf16x8 af[4], bfr[4];
      #pragma unroll
      for (int mt = 0; mt < 4; ++mt) {
        const int R = wr * 64 + mt * 16 + lq;
        af[mt] = *(const bf16x8*)(
            &As[R * 64 + ((ks * 32 + lg * 8) ^ ((R & 7) * 8))]);
      }
      #pragma unroll
      for (int nt = 0; nt < 4; ++nt) {
        const int R = wc * 64 + nt * 16 + lq;
        bfr[nt] = *(const bf16x8*)(
            &Bs[R * 64 + ((ks * 32 + lg * 8) ^ ((R & 7) * 8))]);
      }
      #pragma unroll
      for (int mt = 0; mt < 4; ++mt)
        #pragma unroll
        for (int nt = 0; nt < 4; ++nt)
          acc[mt][nt] = __builtin_amdgcn_mfma_f32_16x16x32_bf16(
              af[mt], bfr[nt], acc[mt][nt], 0, 0, 0);
    }
  }
  #pragma unroll
  for (int nt = 0; nt < 4; ++nt) {
    const int colc = n0 + wc * 64 + nt * 16 + lq;
    const float bcol = bias ? bias[colc] : 0.f;
    #pragma unroll
    for (int mt = 0; mt < 4; ++mt) {
      #pragma unroll
      for (int i = 0; i < 4; ++i) {
        const size_t row = (size_t)(m0 + wr * 64 + mt * 16 + lg * 4 + i);
        float v = acc[mt][nt][i] * scale + bcol;
        if (vt_out) {
          // transposed per-head: vt[(bi*8+h)*64 + d][m], h=colc>>6, d=colc&63
          vt_out[(size_t)((((row >> 10) * 8 + (colc >> 6)) << 6) + (colc & 63)) * MCTX
                 + (row & (MCTX - 1))] = f2bf(v);
        } else if (F32_RES_OUT) {
          ((float*)Cout)[row * N + colc] = v + res[row * N + colc];
        } else {
          ((ushort*)Cout)[row * N + colc] = f2bf(v);
        }
      }
    }
  }
}

// ---------------------------------------------------------------------------
// MERGED PROJECTIONS: Q (512 blocks) + K (128) + V (128, transposed-epilogue)
// in one 768-block launch — 3 blocks/CU co-resident vs two separate phases
// at 2/CU and 1/CU; removes one drain/launch boundary.
// ---------------------------------------------------------------------------
__global__ __launch_bounds__(256) void qkv_kernel(
    const ushort* __restrict__ xnbf, const ushort* __restrict__ ynbf,
    const ushort* __restrict__ wtq, const ushort* __restrict__ wtk,
    const ushort* __restrict__ wtv, const float* __restrict__ bv,
    ushort* __restrict__ qbf, ushort* __restrict__ kbf,
    ushort* __restrict__ vtb) {
  const int id = blockIdx.x;
  if (id < 512) {
    // q = (xn @ Wq) * 0.125 * log2(e)  (softmax runs in exp2 domain)
    gemm_body<false>(xnbf, wtq, nullptr, nullptr, qbf, nullptr,
                     16384, 512, 256, 0.1803368801111204f,
                     (id >> 2) * 128, (id & 3) * 128);
  } else if (id < 640) {
    const int i2 = id - 512;
    gemm_body<false>(ynbf, wtk, nullptr, nullptr, kbf, nullptr,
                     4096, 512, 256, 1.f, (i2 >> 2) * 128, (i2 & 3) * 128);
  } else {
    const int i2 = id - 640;
    gemm_body<false>(ynbf, wtv, bv, nullptr, nullptr, vtb,
                     4096, 512, 256, 1.f, (i2 >> 2) * 128, (i2 & 3) * 128);
  }
}

template <bool F32_RES_OUT>
__global__ __launch_bounds__(256) void mfma_gemm(
    const ushort* __restrict__ A, const ushort* __restrict__ Bt,
    const float* __restrict__ bias, const float* __restrict__ res,
    void* __restrict__ Cout, int M, int N, int K, float scale) {
  gemm_body<F32_RES_OUT>(A, Bt, bias, res, Cout, nullptr, M, N, K, scale,
                         blockIdx.y * 128, blockIdx.x * 128);
}

// ---------------------------------------------------------------------------
// Flash attention, bf16 MFMA, 32x32 tiles + in-register P via permlane swap.
// (r10 structure, measured 56.5 us — unchanged except unroll-2 on key loop.)
// q:[b*n][512] pre-scaled 0.125*log2e; k:[b*m][512]; vt:[b*h][64 d][1024 m].
// Block: (b,h) x 256 q-rows; 8 waves x 32 q-rows (one 32x32 group per wave).
// QK^T: St[2] = mfma_32x32x16(K-frag, Q-frag) over d=64 (8 mfma/tile).
// C-layout (m74/m101): col=q=lane&31, row=key=(reg&3)+8*(reg>>2)+4*(lane>>5).
// Softmax fully in-lane (32 vals) + one shfl_xor(32); exp2 domain; defer-max.
// P -> PV A-frags IN REGISTERS via v_permlane32_swap_b32 (frag=[Sa,Sb,Da,Db]
// valid for BOTH lane halves). PV: 8 mfma_32x32x16.
// LEDGER (do not revisit): 4-wave blocks -13% (r5); gload_lds K/V staging in
// attn -13% (r5); min-waves>4 spills catastrophically (r3); K=16 16x16 PV -7%
// (r8); intra-tile reorder flat (r4); 16x16+LDS-P structure = 61-62us (r7/r9).
// ---------------------------------------------------------------------------
__global__ __launch_bounds__(512, 4) void attn_mfma(
    const ushort* __restrict__ q, const ushort* __restrict__ k,
    const ushort* __restrict__ vt, ushort* __restrict__ ao) {
  // XCD-aware swizzle (bijective: 512 = 8 * 64)
  const int bid = blockIdx.x + 16 * (blockIdx.y + 8 * blockIdx.z);
  const int swz = (bid & 7) * 64 + (bid >> 3);
  const int bi = swz >> 7;
  const int h = (swz >> 4) & 7;
  const int n0 = (swz & 15) * 256;
  const int tile0 = (bid & 3) << 2;        // phase stagger: 0,4,8,12
  __shared__ ushort Ks[2][64 * 64];
  __shared__ ushort Vs[2][64 * 64];
  const int t = threadIdx.x;
  const int l = t & 63, w = t >> 6;
  const int lq32 = l & 31, hi = l >> 5;

  // Q fragments (B operand of QK: B[k=d][col=q], k=(lane>>5)*8+e per d-step)
  bf16x8 bq[4];
  {
    const size_t qrow = (size_t)(bi * HW + n0 + w * 32 + lq32);
    #pragma unroll
    for (int ds = 0; ds < 4; ++ds)
      bq[ds] = *(const bf16x8*)(q + qrow * INNER + h * DHEAD + ds * 16 + hi * 8);
  }

  float m_run = -1e30f, l_run = 0.f;
  f32x16 oacc[2];                           // O[q][d], d-tiles of 32
  #pragma unroll
  for (int dt = 0; dt < 2; ++dt)
    #pragma unroll
    for (int e = 0; e < 16; ++e) oacc[dt][e] = 0.f;

  // staging: 64x64 bf16 tile = 512 uint4; 512 threads -> 1 uint4 each per tile
  const int rr = t >> 3, cc = (t & 7) * 8;
  const ushort* kptr = k + (size_t)(bi * MCTX + rr) * INNER + h * DHEAD + cc;
  const ushort* vptr = vt + (size_t)((bi * HEADS + h) * 64 + rr) * MCTX + cc;
  const int sidx = (rr * 64 + cc) ^ ((rr & 7) << 3);

  {  // stage first tile (tile0) into buffer 0
    const int ms = tile0 << 6;
    uint4 k0v = *(const uint4*)(kptr + (size_t)ms * INNER);
    uint4 v0v = *(const uint4*)(vptr + ms);
    *(uint4*)(&Ks[0][sidx]) = k0v;
    *(uint4*)(&Vs[0][sidx]) = v0v;
  }
  __syncthreads();

  #pragma unroll 2
  for (int it = 0; it < 16; ++it) {
    const int buf = it & 1;
    const bool more = (it + 1) < 16;
    const int mnext = ((tile0 + it + 1) & 15) << 6;
    uint4 kpre{}, vpre{};
    if (more) {  // prefetch next tile; staged to LDS after softmax
      kpre = *(const uint4*)(kptr + (size_t)mnext * INNER);
      vpre = *(const uint4*)(vptr + mnext);
    }
    // QK^T: St[kt][key=32kt+row][q=lane&31] over d=64, A=K-frag from Ks
    f32x16 sc[2];
    #pragma unroll
    for (int kt = 0; kt < 2; ++kt)
      #pragma unroll
      for (int e = 0; e < 16; ++e) sc[kt][e] = 0.f;
    __builtin_amdgcn_s_setprio(1);
    #pragma unroll
    for (int kt = 0; kt < 2; ++kt) {
      #pragma unroll
      for (int ds = 0; ds < 4; ++ds) {
        const int krow = kt * 32 + lq32;
        bf16x8 ak = *(const bf16x8*)(
            &Ks[buf][(krow * 64 + ds * 16 + hi * 8) ^ ((krow & 7) << 3)]);
        sc[kt] = __builtin_amdgcn_mfma_f32_32x32x16_bf16(ak, bq[ds], sc[kt], 0, 0, 0);
      }
    }
    __builtin_amdgcn_s_setprio(0);
    // ---- softmax (q = lane&31; lanes l, l+32 hold complementary keys) ----
    f32x16 mx;
    #pragma unroll
    for (int e = 0; e < 16; ++e) mx[e] = fmaxf(sc[0][e], sc[1][e]);
    #pragma unroll
    for (int e = 0; e < 8; ++e) mx[e] = fmaxf(mx[e], mx[e + 8]);
    #pragma unroll
    for (int e = 0; e < 4; ++e) mx[e] = fmaxf(mx[e], mx[e + 4]);
    float mloc = fmaxf(fmaxf(mx[0], mx[1]), fmaxf(mx[2], mx[3]));
    mloc = fmaxf(mloc, __shfl_xor(mloc, 32));
    // defer-max: only rescale when some q-row's max grew by > 8 (log2 units)
    if (!__all((int)(mloc - m_run <= 8.f))) {
      const float mnew = fmaxf(m_run, mloc);
      const float corr = __builtin_amdgcn_exp2f(m_run - mnew);
      l_run *= corr;
      m_run = mnew;
      #pragma unroll
      for (int r = 0; r < 16; ++r) {
        const int qrow = (r & 3) + 8 * (r >> 2) + 4 * hi;
        float ci = __shfl(corr, qrow);
        oacc[0][r] *= ci; oacc[1][r] *= ci;
      }
    }
    #pragma unroll
    for (int kt = 0; kt < 2; ++kt)
      #pragma unroll
      for (int e = 0; e < 16; ++e)
        sc[kt][e] = __builtin_amdgcn_exp2f(sc[kt][e] - m_run);
    f32x16 s16;
    #pragma unroll
    for (int e = 0; e < 16; ++e) s16[e] = sc[0][e] + sc[1][e];
    #pragma unroll
    for (int e = 0; e < 8; ++e) s16[e] += s16[e + 8];
    #pragma unroll
    for (int e = 0; e < 4; ++e) s16[e] += s16[e + 4];
    float psum = (s16[0] + s16[1]) + (s16[2] + s16[3]);
    psum += __shfl_xor(psum, 32);
    l_run += psum;
    // ---- P -> PV A-frags in registers (pack + permlane32_swap) ----
    bf16x8 pafr[4];
    #pragma unroll
    for (int kt = 0; kt < 2; ++kt) {
      uint wa[4], wb[4];
      #pragma unroll
      for (int r4 = 0; r4 < 4; ++r4) {
        wa[r4] = (uint)f2bf(sc[kt][4 * r4]) | ((uint)f2bf(sc[kt][4 * r4 + 1]) << 16);
        wb[r4] = (uint)f2bf(sc[kt][4 * r4 + 2]) | ((uint)f2bf(sc[kt][4 * r4 + 3]) << 16);
      }
      #pragma unroll
      for (int p2 = 0; p2 < 2; ++p2) {
        uint Sa = wa[2 * p2], Da = wa[2 * p2 + 1];
        uint Sb = wb[2 * p2], Db = wb[2 * p2 + 1];
        asm volatile("v_permlane32_swap_b32 %0, %1" : "+v"(Da), "+v"(Sa));
        asm volatile("v_permlane32_swap_b32 %0, %1" : "+v"(Db), "+v"(Sb));
        uint4 fr;
        fr.x = Sa; fr.y = Sb; fr.z = Da; fr.w = Db;
        pafr[kt * 2 + p2] = *reinterpret_cast<bf16x8*>(&fr);
      }
    }
    // stage next tile into the other buffer (safe: buf^1 last read before
    // the previous barrier); drains during PV
    if (more) {
      *(uint4*)(&Ks[buf ^ 1][sidx]) = kpre;
      *(uint4*)(&Vs[buf ^ 1][sidx]) = vpre;
    }
    // ---- PV: O[q][d] += P @ V, B-frag = V[key][d] from Vs[d][key] ----
    __builtin_amdgcn_s_setprio(1);
    #pragma unroll
    for (int dt = 0; dt < 2; ++dt) {
      const int vrow = dt * 32 + lq32;
      #pragma unroll
      for (int kt16 = 0; kt16 < 4; ++kt16) {
        bf16x8 vb = *(const bf16x8*)(
            &Vs[buf][(vrow * 64 + kt16 * 16 + hi * 8) ^ ((vrow & 7) << 3)]);
        oacc[dt] = __builtin_amdgcn_mfma_f32_32x32x16_bf16(pafr[kt16], vb, oacc[dt], 0, 0, 0);
      }
    }
    __builtin_amdgcn_s_setprio(0);
    __syncthreads();
  }
  const float rl = 1.f / l_run;
  #pragma unroll
  for (int r = 0; r < 16; ++r) {
    const int qrow = (r & 3) + 8 * (r >> 2) + 4 * hi;
    float li = __shfl(rl, qrow);
    const size_t row = (size_t)(bi * HW + n0 + w * 32 + qrow);
    ao[row * INNER + h * DHEAD + lq32] = f2bf(oacc[0][r] * li);
    ao[row * INNER + h * DHEAD + 32 + lq32] = f2bf(oacc[1][r] * li);
  }
}

// ---------------------------------------------------------------------------
extern "C" void kernel_launch(void* const* d_in, const int* in_sizes, int n_in,
                              void* d_out, int out_size, void* d_ws, size_t ws_size,
                              hipStream_t stream) {
  const float* x     = (const float*)d_in[0];
  const float* y     = (const float*)d_in[1];
  const float* ln_xg = (const float*)d_in[2];
  const float* ln_xb = (const float*)d_in[3];
  const float* ln_yg = (const float*)d_in[4];
  const float* ln_yb = (const float*)d_in[5];
  const float* Wq    = (const float*)d_in[6];
  const float* Wk    = (const float*)d_in[7];
  const float* Wv    = (const float*)d_in[8];
  const float* bv    = (const float*)d_in[9];
  const float* Wo    = (const float*)d_in[10];
  const float* bo    = (const float*)d_in[11];
  float* out = (float*)d_out;

  char* p = (char*)d_ws;
  float*  xn   = (float*)p;  p += (size_t)16384 * 256 * 4;
  ushort* xnbf = (ushort*)p; p += (size_t)16384 * 256 * 2;
  ushort* ynbf = (ushort*)p; p += (size_t)4096 * 256 * 2;
  ushort* wtq  = (ushort*)p; p += (size_t)512 * 256 * 2;
  ushort* wtk  = (ushort*)p; p += (size_t)512 * 256 * 2;
  ushort* wtv  = (ushort*)p; p += (size_t)512 * 256 * 2;
  ushort* wto  = (ushort*)p; p += (size_t)256 * 512 * 2;
  ushort* qbf  = (ushort*)p; p += (size_t)16384 * 512 * 2;
  ushort* kbf  = (ushort*)p; p += (size_t)4096 * 512 * 2;
  ushort* vtb  = (ushort*)p; p += (size_t)4096 * 512 * 2;
  ushort* aobf = (ushort*)p; p += (size_t)16384 * 512 * 2;

  // 1) all preprocessing in one launch (ln_x first: longest)
  prep_kernel<<<dim3(512 + 1024 + 128), 256, 0, stream>>>(
      x, ln_xg, ln_xb, xn, xnbf, y, ln_yg, ln_yb, ynbf,
      Wq, Wk, Wv, Wo, wtq, wtk, wtv, wto);
  // 2) Q + K + V projections in one launch (V written transposed per-head)
  qkv_kernel<<<dim3(768), 256, 0, stream>>>(
      xnbf, ynbf, wtq, wtk, wtv, bv, qbf, kbf, vtb);
  // 3) attention
  attn_mfma<<<dim3(HW / 256, HEADS, BATCH), 512, 0, stream>>>(qbf, kbf, vtb, aobf);
  // 4) out = ao @ Wo + bo + xn
  mfma_gemm<true><<<dim3(2, 128), 256, 0, stream>>>(
      aobf, wto, bo, xn, out, 16384, 256, 512, 1.f);
}